// Round 1
// baseline (25085.899 us; speedup 1.0000x reference)
//
#include <hip/hip_runtime.h>

#define NB 36
#define NT 60

// ---------------- one-time prep kernels ----------------

// wt[(cin*9+dd)*Cout + co] = W[(co*Cin+cin)*9 + dd]
template<int Cin,int Cout>
__global__ void k_wt(const float* __restrict__ W, float* __restrict__ wt){
  int i = blockIdx.x*256 + threadIdx.x;
  const int n = Cin*9*Cout;
  if(i>=n) return;
  int co = i % Cout;
  int r  = i / Cout;       // cin*9 + dd
  int cin = r/9, dd = r%9;
  wt[i] = W[(co*Cin+cin)*9 + dd];
}

// xb[t][b][c][h][w] = (data[b][c][h][w][t] > 1) ? 1 : 0
__global__ void k_bin(const float* __restrict__ data, float* __restrict__ xb){
  int i = blockIdx.x*256 + threadIdx.x;
  const int n = NT*NB*2*32*32;
  if(i>=n) return;
  int t = i / (NB*2*32*32);
  int r = i % (NB*2*32*32);   // linear [b][c][h][w] == data's outer index
  xb[i] = (data[(size_t)r*NT + t] > 1.0f) ? 1.0f : 0.0f;
}

// ---------------- fused conv3x3 + LIAF ----------------
// blockDim = (HW, TH); grid.x = B * (HW/TH) * (Cout/CO)
// wt layout: [(cin*9 + dh*3 + dw)*Cout + co]  (uniform index -> s_load)
template<int Cin,int Cout,int HW,int CO,int TH>
__global__ void __launch_bounds__(256)
k_conv_liaf(const float* __restrict__ x, const float* __restrict__ wt,
            const float* __restrict__ bias, float* __restrict__ dm,
            float* __restrict__ out){
  const int NCOG = Cout/CO;
  const int NHG  = HW/TH;
  int bid = blockIdx.x;
  int cog = bid % NCOG;
  int hg  = (bid / NCOG) % NHG;
  int b   = bid / (NCOG*NHG);
  int w = threadIdx.x;
  int h = hg*TH + threadIdx.y;

  float acc[CO];
  #pragma unroll
  for(int i=0;i<CO;i++) acc[i]=0.f;

  const float* xb_ = x + (size_t)b*Cin*HW*HW;
  for(int cin=0; cin<Cin; cin++){
    const float* xc = xb_ + cin*HW*HW;
    #pragma unroll
    for(int dh=0; dh<3; dh++){
      int hh = h + dh - 1;
      bool hv = (hh>=0) && (hh<HW);
      const float* xr = xc + hh*HW;
      float xm = (hv && w>=1)    ? xr[w-1] : 0.f;
      float x0 =  hv             ? xr[w]   : 0.f;
      float xp = (hv && w+1<HW)  ? xr[w+1] : 0.f;
      const float* wp = wt + (cin*9 + dh*3)*Cout + cog*CO;
      #pragma unroll
      for(int co=0; co<CO; co++){
        acc[co] += wp[co]*xm + wp[Cout+co]*x0 + wp[2*Cout+co]*xp;
      }
    }
  }

  int co0 = cog*CO;
  size_t base = ((size_t)b*Cout + co0)*HW*HW + (size_t)h*HW + w;
  #pragma unroll
  for(int co=0; co<CO; co++){
    size_t idx = base + (size_t)co*HW*HW;
    float mem = dm[idx] + acc[co] + bias[co0+co];
    out[idx] = mem > 0.f ? mem : 0.f;
    dm[idx]  = (mem > 0.5f) ? 0.f : mem*0.3f;
  }
}

// ---------------- fused 2x2 avgpool + LIAF ----------------
template<int C,int Hin>
__global__ void k_pool_liaf(const float* __restrict__ in, float* __restrict__ dm,
                            float* __restrict__ out){
  const int Ho = Hin/2;
  int i = blockIdx.x*256 + threadIdx.x;
  const int n = NB*C*Ho*Ho;
  if(i>=n) return;
  int w  = i % Ho;
  int h  = (i/Ho) % Ho;
  int cb = i / (Ho*Ho);           // b*C + c
  const float* p = in + ((size_t)cb*Hin + 2*h)*Hin + 2*w;
  float u = (p[0] + p[1] + p[Hin] + p[Hin+1]) * 0.25f;
  float mem = dm[i] + u;
  out[i] = mem > 0.f ? mem : 0.f;
  dm[i]  = (mem > 0.5f) ? 0.f : mem*0.3f;
}

// ---------------- fused FC(8192->256) + LIAF ----------------
// one wave per output; blockDim=256 (4 outputs/block); grid = 36*256/4 = 2304
__global__ void __launch_bounds__(256)
k_fc1_liaf(const float* __restrict__ in, const float* __restrict__ Wf,
           const float* __restrict__ bias, float* __restrict__ dm,
           float* __restrict__ out){
  int wid  = blockIdx.x*4 + (threadIdx.x >> 6);
  int lane = threadIdx.x & 63;
  int o = wid % 256;
  int b = wid / 256;
  const float4* x4 = (const float4*)(in + (size_t)b*8192);
  const float4* w4 = (const float4*)(Wf + (size_t)o*8192);
  float s = 0.f;
  for(int k=lane; k<2048; k+=64){
    float4 a  = x4[k];
    float4 ww = w4[k];
    s += a.x*ww.x + a.y*ww.y + a.z*ww.z + a.w*ww.w;
  }
  #pragma unroll
  for(int off=32; off>0; off>>=1) s += __shfl_down(s, off, 64);
  if(lane==0){
    int idx = b*256 + o;
    float mem = dm[idx] + s + bias[o];
    out[idx] = mem > 0.f ? mem : 0.f;
    dm[idx]  = (mem > 0.5f) ? 0.f : mem*0.3f;
  }
}

// ---------------- fused FC(256->11) + LIAF + accumulate ----------------
// grid = 36, blockDim = 64
__global__ void k_fc2_liaf(const float* __restrict__ in, const float* __restrict__ Wf,
                           const float* __restrict__ bias, float* __restrict__ dm,
                           float* __restrict__ acc){
  int b = blockIdx.x;
  int lane = threadIdx.x;
  const float* x = in + (size_t)b*256;
  float xv[4];
  #pragma unroll
  for(int j=0;j<4;j++) xv[j] = x[lane + 64*j];
  for(int o=0;o<11;o++){
    const float* wr = Wf + o*256;
    float s = xv[0]*wr[lane] + xv[1]*wr[lane+64] + xv[2]*wr[lane+128] + xv[3]*wr[lane+192];
    #pragma unroll
    for(int off=32; off>0; off>>=1) s += __shfl_down(s, off, 64);
    if(lane==0){
      int idx = b*11 + o;
      float mem = dm[idx] + s + bias[o];
      float outv = mem > 0.f ? mem : 0.f;
      dm[idx] = (mem > 0.5f) ? 0.f : mem*0.3f;
      acc[idx] += outv * (1.0f/60.0f);
    }
  }
}

// ---------------- launch ----------------

extern "C" void kernel_launch(void* const* d_in, const int* in_sizes, int n_in,
                              void* d_out, int out_size, void* d_ws, size_t ws_size,
                              hipStream_t stream) {
  const float* data = (const float*)d_in[0];
  // d_in[1] = win (int, ==60, hardcoded)
  const float* W0  = (const float*)d_in[2];  const float* b0  = (const float*)d_in[3];
  const float* W1  = (const float*)d_in[4];  const float* b1  = (const float*)d_in[5];
  const float* W2  = (const float*)d_in[6];  const float* b2  = (const float*)d_in[7];
  const float* Wf1 = (const float*)d_in[8];  const float* bf1 = (const float*)d_in[9];
  const float* Wf2 = (const float*)d_in[10]; const float* bf2 = (const float*)d_in[11];

  float* ws = (float*)d_ws;
  // sizes (floats)
  const size_t S_XB   = (size_t)NT*NB*2*32*32;   // 4,423,680
  const size_t S_W0T  = 2*9*64;                  // 1,152
  const size_t S_W1T  = 64*9*128;                // 73,728
  const size_t S_W2T  = 128*9*128;               // 147,456
  const size_t S_OUT0 = (size_t)NB*64*32*32;     // 2,359,296
  const size_t S_OUT1 = (size_t)NB*128*32*32;    // 4,718,592
  const size_t S_OP1  = (size_t)NB*128*16*16;    // 1,179,648
  const size_t S_OUT2 = S_OP1;                   // 1,179,648
  const size_t S_OP2  = (size_t)NB*128*8*8;      // 294,912
  const size_t S_OH1  = (size_t)NB*256;          // 9,216

  float* xb    = ws;                 ws += S_XB;
  float* w0t   = ws;                 ws += S_W0T;
  float* w1t   = ws;                 ws += S_W1T;
  float* w2t   = ws;                 ws += S_W2T;
  float* out0  = ws;                 ws += S_OUT0;
  float* out1  = ws;                 ws += S_OUT1;
  float* outp1 = ws;                 ws += S_OP1;
  float* out2  = ws;                 ws += S_OUT2;
  float* outp2 = ws;                 ws += S_OP2;
  float* outh1 = ws;                 ws += S_OH1;
  // decayed-membrane states (dm = mem*0.3*(1-spike)), all contiguous for one memset
  float* dm0   = ws;                 ws += S_OUT0;
  float* dm1   = ws;                 ws += S_OUT1;
  float* dmp1  = ws;                 ws += S_OP1;
  float* dm2   = ws;                 ws += S_OUT2;
  float* dmp2  = ws;                 ws += S_OP2;
  float* dmh1  = ws;                 ws += S_OH1;
  float* dmh2  = ws;                 ws += (size_t)NB*11;

  const size_t dm_floats = S_OUT0 + S_OUT1 + S_OP1 + S_OUT2 + S_OP2 + S_OH1 + (size_t)NB*11;
  hipMemsetAsync(dm0, 0, dm_floats*sizeof(float), stream);
  hipMemsetAsync(d_out, 0, (size_t)NB*11*sizeof(float), stream);

  // one-time prep
  k_bin<<<dim3((S_XB+255)/256), dim3(256), 0, stream>>>(data, xb);
  k_wt<2,64>  <<<dim3((S_W0T+255)/256), dim3(256), 0, stream>>>(W0, w0t);
  k_wt<64,128><<<dim3((S_W1T+255)/256), dim3(256), 0, stream>>>(W1, w1t);
  k_wt<128,128><<<dim3((S_W2T+255)/256), dim3(256), 0, stream>>>(W2, w2t);

  for(int t=0; t<NT; t++){
    const float* xt = xb + (size_t)t*NB*2*32*32;
    // conv0: 2->64 @32x32, 32 couts/thread
    k_conv_liaf<2,64,32,32,8><<<dim3(36*4*2), dim3(32,8), 0, stream>>>(xt, w0t, b0, dm0, out0);
    // conv1: 64->128 @32x32
    k_conv_liaf<64,128,32,32,8><<<dim3(36*4*4), dim3(32,8), 0, stream>>>(out0, w1t, b1, dm1, out1);
    // pool1 + LIAF
    k_pool_liaf<128,32><<<dim3((S_OP1+255)/256), dim3(256), 0, stream>>>(out1, dmp1, outp1);
    // conv2: 128->128 @16x16, 16 couts/thread
    k_conv_liaf<128,128,16,16,16><<<dim3(36*8), dim3(16,16), 0, stream>>>(outp1, w2t, b2, dm2, out2);
    // pool2 + LIAF (output already in flatten order [b][c*64+h*8+w])
    k_pool_liaf<128,16><<<dim3((S_OP2+255)/256), dim3(256), 0, stream>>>(out2, dmp2, outp2);
    // fc1 + LIAF
    k_fc1_liaf<<<dim3(2304), dim3(256), 0, stream>>>(outp2, Wf1, bf1, dmh1, outh1);
    // fc2 + LIAF + accumulate /60 into d_out
    k_fc2_liaf<<<dim3(36), dim3(64), 0, stream>>>(outh1, Wf2, bf2, dmh2, (float*)d_out);
  }
}

// Round 2
// 15846.585 us; speedup vs baseline: 1.5830x; 1.5830x over previous
//
#include <hip/hip_runtime.h>

#define NB 36
#define NT 60

// ---------------- one-time prep kernels ----------------

// wt[(cin*9+dd)*Cout + co] = W[(co*Cin+cin)*9 + dd]
template<int Cin,int Cout>
__global__ void k_wt(const float* __restrict__ W, float* __restrict__ wt){
  int i = blockIdx.x*256 + threadIdx.x;
  const int n = Cin*9*Cout;
  if(i>=n) return;
  int co = i % Cout;
  int r  = i / Cout;       // cin*9 + dd
  int cin = r/9, dd = r%9;
  wt[i] = W[(co*Cin+cin)*9 + dd];
}

// xb[t][b][c][h][w] = (data[b][c][h][w][t] > 1) ? 1 : 0
__global__ void k_bin(const float* __restrict__ data, float* __restrict__ xb){
  int i = blockIdx.x*256 + threadIdx.x;
  const int n = NT*NB*2*32*32;
  if(i>=n) return;
  int t = i / (NB*2*32*32);
  int r = i % (NB*2*32*32);
  xb[i] = (data[(size_t)r*NT + t] > 1.0f) ? 1.0f : 0.0f;
}

// ---------------- fused conv3x3 + LIAF (+ optional avgpool2 + LIAF) ----------------
// blockDim = (HW, TY). Each thread: PX consecutive rows x CO couts at column w.
// Weights staged in LDS once per block; inner loop reads them as float4
// broadcasts (all lanes same address -> conflict-free).
// wt layout: [(cin*9 + dh*3 + dw)*Cout + co]
template<int Cin,int Cout,int HW,int CO,int PX,int TY,bool POOL>
__global__ void __launch_bounds__(HW*TY)
k_conv(const float* __restrict__ x, const float* __restrict__ wt,
       const float* __restrict__ bias, float* __restrict__ dm,
       float* __restrict__ out,   // !POOL: conv analog out [b][Cout][HW][HW]
       float* __restrict__ dmp,   // POOL: pooled LIAF state
       float* __restrict__ outp)  // POOL: pooled analog out [b][Cout][HW/2][HW/2]
{
  const int NCOG = Cout/CO;
  const int TH   = PX*TY;
  const int NHG  = HW/TH;
  const int NH4  = CO/4;
  int bid = blockIdx.x;
  int cog = bid % NCOG;
  int hg  = (bid/NCOG) % NHG;
  int b   = bid/(NCOG*NHG);
  int w   = threadIdx.x;
  int ty  = threadIdx.y;
  int h0  = hg*TH + ty*PX;

  __shared__ __align__(16) float wl[Cin*9*CO];
  const int NTH = HW*TY;
  int tid = ty*HW + w;
  for(int j=tid; j<Cin*9*CO; j+=NTH){
    int c  = j % CO;
    int rr = j / CO;            // cin*9 + dd
    wl[j] = wt[rr*Cout + cog*CO + c];
  }
  __syncthreads();

  float accs[PX][CO];
  #pragma unroll
  for(int p=0;p<PX;p++)
    #pragma unroll
    for(int c=0;c<CO;c++) accs[p][c]=0.f;

  for(int cin=0; cin<Cin; cin++){
    const float* xc = x + ((size_t)b*Cin + cin)*HW*HW;
    float xmv[PX+2], x0v[PX+2], xpv[PX+2];
    #pragma unroll
    for(int r=0;r<PX+2;r++){
      int hh = h0 - 1 + r;
      bool hv = (hh>=0) && (hh<HW);
      const float* xr = xc + hh*HW;
      x0v[r] =  hv            ? xr[w]   : 0.f;
      xmv[r] = (hv && w>0)    ? xr[w-1] : 0.f;
      xpv[r] = (hv && w<HW-1) ? xr[w+1] : 0.f;
    }
    const float4* w4 = (const float4*)(wl + cin*9*CO);
    #pragma unroll
    for(int dh=0;dh<3;dh++){
      float4 wa[NH4], wb[NH4], wc[NH4];
      #pragma unroll
      for(int g=0;g<NH4;g++){
        wa[g] = w4[(dh*3+0)*NH4+g];
        wb[g] = w4[(dh*3+1)*NH4+g];
        wc[g] = w4[(dh*3+2)*NH4+g];
      }
      #pragma unroll
      for(int g=0;g<NH4;g++){
        const float* A  = (const float*)&wa[g];
        const float* Bp = (const float*)&wb[g];
        const float* Cp = (const float*)&wc[g];
        #pragma unroll
        for(int cc=0;cc<4;cc++){
          #pragma unroll
          for(int px=0;px<PX;px++){
            int r = dh+px;
            accs[px][g*4+cc] += A[cc]*xmv[r] + Bp[cc]*x0v[r] + Cp[cc]*xpv[r];
          }
        }
      }
    }
  }

  // epilogue: conv LIAF (+ fused pool LIAF)
  int co0 = cog*CO;
  size_t cb = (size_t)b*Cout;
  #pragma unroll
  for(int co=0; co<CO; co++){
    float bsv = bias[co0+co];
    float vs[PX/2 > 0 ? PX/2 : 1];
    #pragma unroll
    for(int pr=0;pr<PX/2;pr++) vs[pr]=0.f;
    #pragma unroll
    for(int px=0; px<PX; px++){
      size_t idx = (cb + co0 + co)*HW*HW + (size_t)(h0+px)*HW + w;
      float mem = dm[idx] + accs[px][co] + bsv;
      float o = mem > 0.f ? mem : 0.f;
      dm[idx] = (mem > 0.5f) ? 0.f : 0.3f*mem;
      if(POOL) vs[px>>1] += o;
      else     out[idx] = o;
    }
    if(POOL){
      #pragma unroll
      for(int pr=0; pr<PX/2; pr++){
        float s = vs[pr];
        s += __shfl_xor(s, 1, 64);
        if((w&1)==0){
          int ph = (h0>>1)+pr, pw = w>>1;
          size_t pidx = (cb + co0 + co)*(HW/2)*(HW/2) + (size_t)ph*(HW/2) + pw;
          float pm = dmp[pidx] + s*0.25f;
          outp[pidx] = pm > 0.f ? pm : 0.f;
          dmp[pidx]  = (pm > 0.5f) ? 0.f : 0.3f*pm;
        }
      }
    }
  }
}

// ---------------- fused FC(8192->256) + LIAF ----------------
__global__ void __launch_bounds__(256)
k_fc1_liaf(const float* __restrict__ in, const float* __restrict__ Wf,
           const float* __restrict__ bias, float* __restrict__ dm,
           float* __restrict__ out){
  int wid  = blockIdx.x*4 + (threadIdx.x >> 6);
  int lane = threadIdx.x & 63;
  int o = wid % 256;
  int b = wid / 256;
  const float4* x4 = (const float4*)(in + (size_t)b*8192);
  const float4* w4 = (const float4*)(Wf + (size_t)o*8192);
  float s = 0.f;
  for(int k=lane; k<2048; k+=64){
    float4 a  = x4[k];
    float4 ww = w4[k];
    s += a.x*ww.x + a.y*ww.y + a.z*ww.z + a.w*ww.w;
  }
  #pragma unroll
  for(int off=32; off>0; off>>=1) s += __shfl_down(s, off, 64);
  if(lane==0){
    int idx = b*256 + o;
    float mem = dm[idx] + s + bias[o];
    out[idx] = mem > 0.f ? mem : 0.f;
    dm[idx]  = (mem > 0.5f) ? 0.f : mem*0.3f;
  }
}

// ---------------- fused FC(256->11) + LIAF + accumulate ----------------
__global__ void k_fc2_liaf(const float* __restrict__ in, const float* __restrict__ Wf,
                           const float* __restrict__ bias, float* __restrict__ dm,
                           float* __restrict__ acc){
  int b = blockIdx.x;
  int lane = threadIdx.x;
  const float* x = in + (size_t)b*256;
  float xv[4];
  #pragma unroll
  for(int j=0;j<4;j++) xv[j] = x[lane + 64*j];
  for(int o=0;o<11;o++){
    const float* wr = Wf + o*256;
    float s = xv[0]*wr[lane] + xv[1]*wr[lane+64] + xv[2]*wr[lane+128] + xv[3]*wr[lane+192];
    #pragma unroll
    for(int off=32; off>0; off>>=1) s += __shfl_down(s, off, 64);
    if(lane==0){
      int idx = b*11 + o;
      float mem = dm[idx] + s + bias[o];
      float outv = mem > 0.f ? mem : 0.f;
      dm[idx] = (mem > 0.5f) ? 0.f : mem*0.3f;
      acc[idx] += outv * (1.0f/60.0f);
    }
  }
}

// ---------------- launch ----------------

extern "C" void kernel_launch(void* const* d_in, const int* in_sizes, int n_in,
                              void* d_out, int out_size, void* d_ws, size_t ws_size,
                              hipStream_t stream) {
  const float* data = (const float*)d_in[0];
  const float* W0  = (const float*)d_in[2];  const float* b0  = (const float*)d_in[3];
  const float* W1  = (const float*)d_in[4];  const float* b1  = (const float*)d_in[5];
  const float* W2  = (const float*)d_in[6];  const float* b2  = (const float*)d_in[7];
  const float* Wf1 = (const float*)d_in[8];  const float* bf1 = (const float*)d_in[9];
  const float* Wf2 = (const float*)d_in[10]; const float* bf2 = (const float*)d_in[11];

  float* ws = (float*)d_ws;
  const size_t S_XB   = (size_t)NT*NB*2*32*32;
  const size_t S_W0T  = 2*9*64;
  const size_t S_W1T  = 64*9*128;
  const size_t S_W2T  = 128*9*128;
  const size_t S_OUT0 = (size_t)NB*64*32*32;
  const size_t S_DM1  = (size_t)NB*128*32*32;
  const size_t S_OP1  = (size_t)NB*128*16*16;
  const size_t S_OP2  = (size_t)NB*128*8*8;
  const size_t S_OH1  = (size_t)NB*256;

  float* xb    = ws;  ws += S_XB;
  float* w0t   = ws;  ws += S_W0T;
  float* w1t   = ws;  ws += S_W1T;
  float* w2t   = ws;  ws += S_W2T;
  float* out0  = ws;  ws += S_OUT0;
  float* outp1 = ws;  ws += S_OP1;
  float* outp2 = ws;  ws += S_OP2;
  float* outh1 = ws;  ws += S_OH1;
  // LIAF decayed-membrane states (dm = mem*0.3*(1-spike)), contiguous for one memset
  float* dm0   = ws;  ws += S_OUT0;
  float* dm1   = ws;  ws += S_DM1;
  float* dmp1  = ws;  ws += S_OP1;
  float* dm2   = ws;  ws += S_OP1;
  float* dmp2  = ws;  ws += S_OP2;
  float* dmh1  = ws;  ws += S_OH1;
  float* dmh2  = ws;  ws += (size_t)NB*11;

  const size_t dm_floats = S_OUT0 + S_DM1 + S_OP1 + S_OP1 + S_OP2 + S_OH1 + (size_t)NB*11;
  hipMemsetAsync(dm0, 0, dm_floats*sizeof(float), stream);
  hipMemsetAsync(d_out, 0, (size_t)NB*11*sizeof(float), stream);

  k_bin<<<dim3((S_XB+255)/256), dim3(256), 0, stream>>>(data, xb);
  k_wt<2,64>   <<<dim3((S_W0T+255)/256), dim3(256), 0, stream>>>(W0, w0t);
  k_wt<64,128> <<<dim3((S_W1T+255)/256), dim3(256), 0, stream>>>(W1, w1t);
  k_wt<128,128><<<dim3((S_W2T+255)/256), dim3(256), 0, stream>>>(W2, w2t);

  for(int t=0; t<NT; t++){
    const float* xt = xb + (size_t)t*NB*2*32*32;
    // conv0: 2->64 @32x32, CO=8, PX=2, TY=8 -> grid 36*2*8=576 blocks of 256
    k_conv<2,64,32,8,2,8,false><<<dim3(36*2*8), dim3(32,8), 0, stream>>>(
        xt, w0t, b0, dm0, out0, nullptr, nullptr);
    // conv1+pool1: 64->128 @32x32, CO=8, PX=4, TY=8 -> grid 36*16=576 blocks of 256
    k_conv<64,128,32,8,4,8,true><<<dim3(36*16), dim3(32,8), 0, stream>>>(
        out0, w1t, b1, dm1, nullptr, dmp1, outp1);
    // conv2+pool2: 128->128 @16x16, CO=4, PX=2, TY=8 -> grid 36*32=1152 blocks of 128
    k_conv<128,128,16,4,2,8,true><<<dim3(36*32), dim3(16,8), 0, stream>>>(
        outp1, w2t, b2, dm2, nullptr, dmp2, outp2);
    // fc1 + LIAF
    k_fc1_liaf<<<dim3(2304), dim3(256), 0, stream>>>(outp2, Wf1, bf1, dmh1, outh1);
    // fc2 + LIAF + accumulate /60 into d_out
    k_fc2_liaf<<<dim3(36), dim3(64), 0, stream>>>(outh1, Wf2, bf2, dmh2, (float*)d_out);
  }
}